// Round 1
// baseline (1149.435 us; speedup 1.0000x reference)
//
#include <hip/hip_runtime.h>
#include <cstdint>
#include <cstddef>

// B=2 L=2048 HIDDEN=2560 NH=16 NKV=4 HD=256 INNER=4096
// QKV combined N = 8192 (q+gate) + 1024 (k) + 1024 (v) = 10240
#define NQKV 10240

typedef __bf16 bf16;
typedef __attribute__((ext_vector_type(4))) __bf16 bvec4;
typedef __attribute__((ext_vector_type(8))) __bf16 bvec8;
typedef __attribute__((ext_vector_type(4))) float fvec4;

__device__ __forceinline__ void gll16(const bf16* g, bf16* l) {
  // async global->LDS, 16B/lane; LDS dest = wave-uniform base + lane*16
  __builtin_amdgcn_global_load_lds(
      (const __attribute__((address_space(1))) void*)g,
      (__attribute__((address_space(3))) void*)l, 16, 0, 0);
}

// ---------------- fp32 -> bf16 flat convert ----------------
__global__ __launch_bounds__(256) void cvt_f32_bf16(const float* __restrict__ x,
                                                    bf16* __restrict__ y, int n) {
  int i = (blockIdx.x * 256 + threadIdx.x) * 4;
  if (i < n) {
    float4 v = *(const float4*)(x + i);
    bvec4 o;
    o.x = (bf16)v.x; o.y = (bf16)v.y; o.z = (bf16)v.z; o.w = (bf16)v.w;
    *(bvec4*)(y + i) = o;
  }
}

// ---------------- W (K x N) fp32 -> Wt (N x K) bf16 ----------------
__global__ __launch_bounds__(256) void wtrans(const float* __restrict__ W,
                                              bf16* __restrict__ Wt, int K, int N) {
  __shared__ float t[64][65];
  int n0 = blockIdx.x * 64, k0 = blockIdx.y * 64;
  int tx = threadIdx.x & 63, tg = threadIdx.x >> 6;
#pragma unroll
  for (int i = 0; i < 16; ++i) {
    int r = tg * 16 + i;
    t[r][tx] = W[(size_t)(k0 + r) * N + n0 + tx];
  }
  __syncthreads();
#pragma unroll
  for (int i = 0; i < 16; ++i) {
    int r = tg * 16 + i;
    Wt[(size_t)(n0 + r) * K + k0 + tx] = (bf16)t[tx][r];
  }
}

// ---------------- V columns of QKV -> Vt (b,kv,d,L) bf16 ----------------
__global__ __launch_bounds__(256) void vtrans(const bf16* __restrict__ QKV,
                                              bf16* __restrict__ Vt) {
  __shared__ bf16 t[64][65];
  int l0 = blockIdx.x * 64, dd0 = blockIdx.y * 64;
  int bkv = blockIdx.z, b = bkv >> 2, kv = bkv & 3;
  int tx = threadIdx.x & 63, tg = threadIdx.x >> 6;
#pragma unroll
  for (int i = 0; i < 16; ++i) {
    int r = tg * 16 + i;
    t[r][tx] = QKV[(size_t)(b * 2048 + l0 + r) * NQKV + 9216 + kv * 256 + dd0 + tx];
  }
  __syncthreads();
#pragma unroll
  for (int i = 0; i < 16; ++i) {
    int r = tg * 16 + i;
    Vt[((size_t)bkv * 256 + dd0 + r) * 2048 + l0 + tx] = t[tx][r];
  }
}

// ---------------- RMSNorm + RoPE: QKV -> Qn (b,h,l,d), Kn (b,kv,l,d) ----------------
// one wave per 256-elem head vector; 4096 tokens * (16 q + 4 k) units
__global__ __launch_bounds__(256) void norm_rope(const bf16* __restrict__ QKV,
    const float* __restrict__ cosT, const float* __restrict__ sinT,
    const float* __restrict__ qw, const float* __restrict__ kw,
    bf16* __restrict__ Qn, bf16* __restrict__ Kn) {
  int u = blockIdx.x * 4 + (threadIdx.x >> 6);
  int lane = threadIdx.x & 63;
  int token = u / 20, slot = u - token * 20;
  int b = token >> 11, l = token & 2047;
  int d0 = lane * 4;
  const float* w;
  int col0;
  bf16* outp;
  if (slot < 16) {
    col0 = slot * 256; w = qw;
    outp = Qn + ((size_t)((b * 16 + slot) * 2048 + l)) * 256;
  } else {
    int kv = slot - 16;
    col0 = 8192 + kv * 256; w = kw;
    outp = Kn + ((size_t)((b * 4 + kv) * 2048 + l)) * 256;
  }
  bvec4 xi = *(const bvec4*)(QKV + (size_t)token * NQKV + col0 + d0);
  float x[4];
#pragma unroll
  for (int j = 0; j < 4; ++j) x[j] = (float)xi[j];
  float ss = x[0] * x[0] + x[1] * x[1] + x[2] * x[2] + x[3] * x[3];
#pragma unroll
  for (int off = 32; off; off >>= 1) ss += __shfl_xor(ss, off);
  float rn = rsqrtf(ss * (1.0f / 256.0f) + 1e-6f);
  float xn[4];
#pragma unroll
  for (int j = 0; j < 4; ++j) xn[j] = x[j] * rn * w[d0 + j];
  bvec4 o;
#pragma unroll
  for (int j = 0; j < 4; ++j) {
    // rotate-half: d<128 pairs with d+128 (negated), d>=128 pairs with d-128
    float other = __shfl_xor(xn[j], 32);
    float rot = (lane < 32) ? -other : other;
    float c = cosT[(size_t)l * 256 + d0 + j];
    float s = sinT[(size_t)l * 256 + d0 + j];
    o[j] = (bf16)(xn[j] * c + rot * s);
  }
  *(bvec4*)(outp + d0) = o;
}

// ---------------- m97-style GEMM: C[M][N] = A[M][K] * B[N][K]^T ----------------
// 128x128 tile, BK=32, 4 waves in 2x2, 4x4 16x16x32 MFMA per wave
template <typename OutT>
__global__ __launch_bounds__(256) void gemm_bt(const bf16* __restrict__ A,
                                               const bf16* __restrict__ B,
                                               OutT* __restrict__ C,
                                               int N, int Kd) {
  __shared__ alignas(16) bf16 As[4096];
  __shared__ alignas(16) bf16 Bs[4096];
  int tid = threadIdx.x, wave = tid >> 6, lane = tid & 63;
  int quad = lane >> 4, l15 = lane & 15;
  int wm = wave >> 1, wn = wave & 1;
  int m0 = blockIdx.y * 128, n0 = blockIdx.x * 128;
  const fvec4 FZ = {0.f, 0.f, 0.f, 0.f};
  fvec4 acc[4][4];
#pragma unroll
  for (int i = 0; i < 4; ++i)
#pragma unroll
    for (int j = 0; j < 4; ++j) acc[i][j] = FZ;
  int ar = lane >> 2;        // row within 16-row staging segment
  int ac = (lane & 3) * 8;   // 8-elem (16B) column chunk
  for (int kt = 0; kt < Kd; kt += 32) {
    __syncthreads();
#pragma unroll
    for (int i = 0; i < 2; ++i) {
      int seg = wave * 2 + i;  // 0..7, 1KB per wave-inst
      int row = seg * 16 + ar;
      gll16(A + (size_t)(m0 + row) * Kd + kt + ac, As + seg * 512);
      gll16(B + (size_t)(n0 + row) * Kd + kt + ac, Bs + seg * 512);
    }
    __syncthreads();
    bvec8 af[4], bfv[4];
#pragma unroll
    for (int t = 0; t < 4; ++t) {
      af[t]  = *(const bvec8*)(As + (wm * 64 + t * 16 + l15) * 32 + quad * 8);
      bfv[t] = *(const bvec8*)(Bs + (wn * 64 + t * 16 + l15) * 32 + quad * 8);
    }
#pragma unroll
    for (int mt = 0; mt < 4; ++mt)
#pragma unroll
      for (int nt = 0; nt < 4; ++nt)
        acc[mt][nt] = __builtin_amdgcn_mfma_f32_16x16x32_bf16(af[mt], bfv[nt],
                                                              acc[mt][nt], 0, 0, 0);
  }
  // C/D layout: row = quad*4+reg, col = lane&15 (m89/m91-verified)
#pragma unroll
  for (int mt = 0; mt < 4; ++mt)
#pragma unroll
    for (int nt = 0; nt < 4; ++nt)
#pragma unroll
      for (int r = 0; r < 4; ++r) {
        int row = m0 + wm * 64 + mt * 16 + quad * 4 + r;
        int col = n0 + wn * 64 + nt * 16 + l15;
        C[(size_t)row * N + col] = (OutT)acc[mt][nt][r];
      }
}

// ---------------- causal flash attention + SiLU-gate epilogue ----------------
// grid (qtile=32, bh=32); block 256 = 4 waves; wave owns 16 Q rows.
// LDS: Ks[64][256] (32KB) + Vts[256][64] (32KB) = 64KB; P (4x16x64, 8KB)
// aliases Ks after a barrier guarantees all QK^T fragment reads are done.
__global__ __launch_bounds__(256, 2) void flash(const bf16* __restrict__ Q,
    const bf16* __restrict__ K, const bf16* __restrict__ Vt,
    const bf16* __restrict__ QKV, bf16* __restrict__ Og) {
  __shared__ alignas(16) bf16 smem[32768];
  bf16* Ks = smem;
  bf16* Vts = smem + 16384;

  int qt = blockIdx.x, q0 = qt * 64;
  int bh = blockIdx.y, b = bh >> 4, h = bh & 15, kvh = h >> 2;
  int tid = threadIdx.x, wave = tid >> 6, lane = tid & 63;
  int quad = lane >> 4, l15 = lane & 15;

  const bf16* Qb = Q + ((size_t)(b * 16 + h) * 2048 + q0) * 256;
  const bf16* Kb = K + ((size_t)(b * 4 + kvh) * 2048) * 256;
  const bf16* Vb = Vt + ((size_t)(b * 4 + kvh) * 256) * 2048;

  // Q fragments resident in VGPRs, pre-scaled by 1/sqrt(256)=2^-4 (exact in bf16)
  bvec8 qf[8];
  {
    int qrow = wave * 16 + l15;
#pragma unroll
    for (int kk = 0; kk < 8; ++kk) {
      bvec8 v = *(const bvec8*)(Qb + (size_t)qrow * 256 + kk * 32 + quad * 8);
#pragma unroll
      for (int j = 0; j < 8; ++j) v[j] = (bf16)((float)v[j] * 0.0625f);
      qf[kk] = v;
    }
  }

  const fvec4 FZ = {0.f, 0.f, 0.f, 0.f};
  fvec4 acc[16];
#pragma unroll
  for (int i = 0; i < 16; ++i) acc[i] = FZ;
  float m_run[4], l_run[4];
#pragma unroll
  for (int r = 0; r < 4; ++r) { m_run[r] = -3.0e38f; l_run[r] = 0.f; }

  int nk = qt + 1;  // causal: K tiles 0..qt
  for (int kt = 0; kt < nk; ++kt) {
    int k0 = kt * 64;
    __syncthreads();  // prior iter's LDS readers done before restaging
#pragma unroll
    for (int i = 0; i < 8; ++i) {
      int seg = wave * 8 + i;  // 0..31, 1KB per wave-inst
      gll16(Kb + (size_t)(k0 + seg * 2 + (lane >> 5)) * 256 + (lane & 31) * 8,
            Ks + seg * 512);
      gll16(Vb + (size_t)(seg * 8 + (lane >> 3)) * 2048 + k0 + (lane & 7) * 8,
            Vts + seg * 512);
    }
    __syncthreads();  // tiles visible (barrier drains vmcnt)

    // S = Q K^T : 4 n-tiles x 8 k-steps
    fvec4 s[4];
#pragma unroll
    for (int nt = 0; nt < 4; ++nt) {
      s[nt] = FZ;
#pragma unroll
      for (int ks = 0; ks < 8; ++ks) {
        bvec8 kf = *(const bvec8*)(Ks + (size_t)(nt * 16 + l15) * 256 + ks * 32 + quad * 8);
        s[nt] = __builtin_amdgcn_mfma_f32_16x16x32_bf16(qf[ks], kf, s[nt], 0, 0, 0);
      }
    }
    __syncthreads();  // ALL waves' Ks reads done -> P may alias Ks

    if (kt == nk - 1) {  // only the diagonal tile masks
#pragma unroll
      for (int nt = 0; nt < 4; ++nt)
#pragma unroll
        for (int r = 0; r < 4; ++r)
          if (k0 + nt * 16 + l15 > q0 + wave * 16 + quad * 4 + r) s[nt][r] = -3.0e38f;
    }
    float alpha[4], rs[4];
#pragma unroll
    for (int r = 0; r < 4; ++r) {
      float m = fmaxf(fmaxf(s[0][r], s[1][r]), fmaxf(s[2][r], s[3][r]));
#pragma unroll
      for (int off = 8; off; off >>= 1) m = fmaxf(m, __shfl_xor(m, off));
      float Mn = fmaxf(m_run[r], m);
      alpha[r] = __expf(m_run[r] - Mn);
      m_run[r] = Mn;
      rs[r] = 0.f;
    }
    bf16* Pw = smem + wave * 1024;  // wave-private 16x64 P tile (aliases Ks)
#pragma unroll
    for (int nt = 0; nt < 4; ++nt)
#pragma unroll
      for (int r = 0; r < 4; ++r) {
        float p = __expf(s[nt][r] - m_run[r]);
        rs[r] += p;
        Pw[(quad * 4 + r) * 64 + nt * 16 + l15] = (bf16)p;
      }
#pragma unroll
    for (int r = 0; r < 4; ++r) {
#pragma unroll
      for (int off = 8; off; off >>= 1) rs[r] += __shfl_xor(rs[r], off);
      l_run[r] = l_run[r] * alpha[r] + rs[r];
    }
#pragma unroll
    for (int nt = 0; nt < 16; ++nt)
#pragma unroll
      for (int r = 0; r < 4; ++r) acc[nt][r] *= alpha[r];
    __syncthreads();  // P writes visible

    // O += P (16x64) * Vtile (64x256); Vts is d-major so B-frags are contiguous
#pragma unroll
    for (int ks = 0; ks < 2; ++ks) {
      bvec8 pf = *(const bvec8*)(Pw + l15 * 64 + ks * 32 + quad * 8);
#pragma unroll
      for (int nt = 0; nt < 16; ++nt) {
        bvec8 vf = *(const bvec8*)(Vts + (size_t)(nt * 16 + l15) * 64 + ks * 32 + quad * 8);
        acc[nt] = __builtin_amdgcn_mfma_f32_16x16x32_bf16(pf, vf, acc[nt], 0, 0, 0);
      }
    }
  }

  // epilogue: O/l * silu(gate), write token-major (b*2048+l, h*256+d)
#pragma unroll
  for (int r = 0; r < 4; ++r) {
    int token = b * 2048 + q0 + wave * 16 + quad * 4 + r;
    float inv = 1.0f / l_run[r];
#pragma unroll
    for (int nt = 0; nt < 16; ++nt) {
      int col = h * 256 + nt * 16 + l15;
      float g = (float)QKV[(size_t)token * NQKV + 4096 + col];
      float silu = g / (1.0f + __expf(-g));
      Og[(size_t)token * 4096 + col] = (bf16)(acc[nt][r] * inv * silu);
    }
  }
}

extern "C" void kernel_launch(void* const* d_in, const int* in_sizes, int n_in,
                              void* d_out, int out_size, void* d_ws, size_t ws_size,
                              hipStream_t stream) {
  const float* hs   = (const float*)d_in[0];
  const float* cosT = (const float*)d_in[1];
  const float* sinT = (const float*)d_in[2];
  const float* Wq   = (const float*)d_in[3];
  const float* Wk   = (const float*)d_in[4];
  const float* Wv   = (const float*)d_in[5];
  const float* Wo   = (const float*)d_in[6];
  const float* qw   = (const float*)d_in[7];
  const float* kw   = (const float*)d_in[8];
  float* out = (float*)d_out;

  char* p = (char*)d_ws;
  auto alloc = [&](size_t bytes) {
    char* r = p;
    p += (bytes + 255) & ~(size_t)255;
    return r;
  };
  bf16* Xb    = (bf16*)alloc((size_t)4096 * 2560 * 2);    // hidden bf16
  bf16* Wqkvt = (bf16*)alloc((size_t)10240 * 2560 * 2);   // [Wq|Wk|Wv]^T bf16
  bf16* Wot   = (bf16*)alloc((size_t)2560 * 4096 * 2);    // Wo^T bf16
  bf16* QKV   = (bf16*)alloc((size_t)4096 * 10240 * 2);   // q|gate|k|v token-major
  bf16* Qn    = (bf16*)alloc((size_t)2 * 16 * 2048 * 256 * 2);
  bf16* Kn    = (bf16*)alloc((size_t)2 * 4 * 2048 * 256 * 2);
  bf16* Vtb   = (bf16*)alloc((size_t)2 * 4 * 256 * 2048 * 2);
  bf16* Og    = (bf16*)alloc((size_t)4096 * 4096 * 2);    // gated attn, token-major
  // total ~262 MB of d_ws

  cvt_f32_bf16<<<10240, 256, 0, stream>>>(hs, Xb, 4096 * 2560);
  wtrans<<<dim3(128, 40), 256, 0, stream>>>(Wq, Wqkvt, 2560, 8192);
  wtrans<<<dim3(16, 40), 256, 0, stream>>>(Wk, Wqkvt + (size_t)8192 * 2560, 2560, 1024);
  wtrans<<<dim3(16, 40), 256, 0, stream>>>(Wv, Wqkvt + (size_t)9216 * 2560, 2560, 1024);
  wtrans<<<dim3(40, 64), 256, 0, stream>>>(Wo, Wot, 4096, 2560);

  gemm_bt<bf16><<<dim3(80, 32), 256, 0, stream>>>(Xb, Wqkvt, QKV, 10240, 2560);

  norm_rope<<<20480, 256, 0, stream>>>(QKV, cosT, sinT, qw, kw, Qn, Kn);
  vtrans<<<dim3(32, 4, 8), 256, 0, stream>>>(QKV, Vtb);

  flash<<<dim3(32, 32), 256, 0, stream>>>(Qn, Kn, Vtb, QKV, Og);

  gemm_bt<float><<<dim3(20, 32), 256, 0, stream>>>(Og, Wot, out, 2560, 4096);
}

// Round 2
// 932.502 us; speedup vs baseline: 1.2326x; 1.2326x over previous
//
#include <hip/hip_runtime.h>
#include <cstdint>
#include <cstddef>

// B=2 L=2048 HIDDEN=2560 NH=16 NKV=4 HD=256 INNER=4096
// QKV combined N = 8192 (q+gate) + 1024 (k) + 1024 (v) = 10240
#define NQKV 10240

typedef __bf16 bf16;
typedef __attribute__((ext_vector_type(4))) __bf16 bvec4;
typedef __attribute__((ext_vector_type(8))) __bf16 bvec8;
typedef __attribute__((ext_vector_type(4))) float fvec4;

__device__ __forceinline__ void gll16(const bf16* g, bf16* l) {
  // async global->LDS, 16B/lane; LDS dest = wave-uniform base + lane*16
  __builtin_amdgcn_global_load_lds(
      (const __attribute__((address_space(1))) void*)g,
      (__attribute__((address_space(3))) void*)l, 16, 0, 0);
}

// ---------------- fp32 -> bf16 flat convert ----------------
__global__ __launch_bounds__(256) void cvt_f32_bf16(const float* __restrict__ x,
                                                    bf16* __restrict__ y, int n) {
  int i = (blockIdx.x * 256 + threadIdx.x) * 4;
  if (i < n) {
    float4 v = *(const float4*)(x + i);
    bvec4 o;
    o.x = (bf16)v.x; o.y = (bf16)v.y; o.z = (bf16)v.z; o.w = (bf16)v.w;
    *(bvec4*)(y + i) = o;
  }
}

// ---------------- W (K x N) fp32 -> Wt (N x K) bf16 ----------------
__global__ __launch_bounds__(256) void wtrans(const float* __restrict__ W,
                                              bf16* __restrict__ Wt, int K, int N) {
  __shared__ float t[64][65];
  int n0 = blockIdx.x * 64, k0 = blockIdx.y * 64;
  int tx = threadIdx.x & 63, tg = threadIdx.x >> 6;
#pragma unroll
  for (int i = 0; i < 16; ++i) {
    int r = tg * 16 + i;
    t[r][tx] = W[(size_t)(k0 + r) * N + n0 + tx];
  }
  __syncthreads();
#pragma unroll
  for (int i = 0; i < 16; ++i) {
    int r = tg * 16 + i;
    Wt[(size_t)(n0 + r) * K + k0 + tx] = (bf16)t[tx][r];
  }
}

// ---------------- V columns of QKV -> Vt (b,kv,d,L) bf16 ----------------
__global__ __launch_bounds__(256) void vtrans(const bf16* __restrict__ QKV,
                                              bf16* __restrict__ Vt) {
  __shared__ bf16 t[64][65];
  int l0 = blockIdx.x * 64, dd0 = blockIdx.y * 64;
  int bkv = blockIdx.z, b = bkv >> 2, kv = bkv & 3;
  int tx = threadIdx.x & 63, tg = threadIdx.x >> 6;
#pragma unroll
  for (int i = 0; i < 16; ++i) {
    int r = tg * 16 + i;
    t[r][tx] = QKV[(size_t)(b * 2048 + l0 + r) * NQKV + 9216 + kv * 256 + dd0 + tx];
  }
  __syncthreads();
#pragma unroll
  for (int i = 0; i < 16; ++i) {
    int r = tg * 16 + i;
    Vt[((size_t)bkv * 256 + dd0 + r) * 2048 + l0 + tx] = t[tx][r];
  }
}

// ---------------- RMSNorm + RoPE: QKV -> Qn (b,h,l,d), Kn (b,kv,l,d) ----------------
__global__ __launch_bounds__(256) void norm_rope(const bf16* __restrict__ QKV,
    const float* __restrict__ cosT, const float* __restrict__ sinT,
    const float* __restrict__ qw, const float* __restrict__ kw,
    bf16* __restrict__ Qn, bf16* __restrict__ Kn) {
  int u = blockIdx.x * 4 + (threadIdx.x >> 6);
  int lane = threadIdx.x & 63;
  int token = u / 20, slot = u - token * 20;
  int b = token >> 11, l = token & 2047;
  int d0 = lane * 4;
  const float* w;
  int col0;
  bf16* outp;
  if (slot < 16) {
    col0 = slot * 256; w = qw;
    outp = Qn + ((size_t)((b * 16 + slot) * 2048 + l)) * 256;
  } else {
    int kv = slot - 16;
    col0 = 8192 + kv * 256; w = kw;
    outp = Kn + ((size_t)((b * 4 + kv) * 2048 + l)) * 256;
  }
  bvec4 xi = *(const bvec4*)(QKV + (size_t)token * NQKV + col0 + d0);
  float x[4];
#pragma unroll
  for (int j = 0; j < 4; ++j) x[j] = (float)xi[j];
  float ss = x[0] * x[0] + x[1] * x[1] + x[2] * x[2] + x[3] * x[3];
#pragma unroll
  for (int off = 32; off; off >>= 1) ss += __shfl_xor(ss, off);
  float rn = rsqrtf(ss * (1.0f / 256.0f) + 1e-6f);
  float xn[4];
#pragma unroll
  for (int j = 0; j < 4; ++j) xn[j] = x[j] * rn * w[d0 + j];
  bvec4 o;
#pragma unroll
  for (int j = 0; j < 4; ++j) {
    float other = __shfl_xor(xn[j], 32);
    float rot = (lane < 32) ? -other : other;
    float c = cosT[(size_t)l * 256 + d0 + j];
    float s = sinT[(size_t)l * 256 + d0 + j];
    o[j] = (bf16)(xn[j] * c + rot * s);
  }
  *(bvec4*)(outp + d0) = o;
}

// ---------------- m97-style GEMM: C[M][N] = A[M][K] * B[N][K]^T ----------------
template <typename OutT>
__global__ __launch_bounds__(256) void gemm_bt(const bf16* __restrict__ A,
                                               const bf16* __restrict__ B,
                                               OutT* __restrict__ C,
                                               int N, int Kd) {
  __shared__ alignas(16) bf16 As[4096];
  __shared__ alignas(16) bf16 Bs[4096];
  int tid = threadIdx.x, wave = tid >> 6, lane = tid & 63;
  int quad = lane >> 4, l15 = lane & 15;
  int wm = wave >> 1, wn = wave & 1;
  int m0 = blockIdx.y * 128, n0 = blockIdx.x * 128;
  const fvec4 FZ = {0.f, 0.f, 0.f, 0.f};
  fvec4 acc[4][4];
#pragma unroll
  for (int i = 0; i < 4; ++i)
#pragma unroll
    for (int j = 0; j < 4; ++j) acc[i][j] = FZ;
  int ar = lane >> 2;
  int ac = (lane & 3) * 8;
  for (int kt = 0; kt < Kd; kt += 32) {
    __syncthreads();
#pragma unroll
    for (int i = 0; i < 2; ++i) {
      int seg = wave * 2 + i;
      int row = seg * 16 + ar;
      gll16(A + (size_t)(m0 + row) * Kd + kt + ac, As + seg * 512);
      gll16(B + (size_t)(n0 + row) * Kd + kt + ac, Bs + seg * 512);
    }
    __syncthreads();
    bvec8 af[4], bfv[4];
#pragma unroll
    for (int t = 0; t < 4; ++t) {
      af[t]  = *(const bvec8*)(As + (wm * 64 + t * 16 + l15) * 32 + quad * 8);
      bfv[t] = *(const bvec8*)(Bs + (wn * 64 + t * 16 + l15) * 32 + quad * 8);
    }
#pragma unroll
    for (int mt = 0; mt < 4; ++mt)
#pragma unroll
      for (int nt = 0; nt < 4; ++nt)
        acc[mt][nt] = __builtin_amdgcn_mfma_f32_16x16x32_bf16(af[mt], bfv[nt],
                                                              acc[mt][nt], 0, 0, 0);
  }
#pragma unroll
  for (int mt = 0; mt < 4; ++mt)
#pragma unroll
    for (int nt = 0; nt < 4; ++nt)
#pragma unroll
      for (int r = 0; r < 4; ++r) {
        int row = m0 + wm * 64 + mt * 16 + quad * 4 + r;
        int col = n0 + wn * 64 + nt * 16 + l15;
        C[(size_t)row * N + col] = (OutT)acc[mt][nt][r];
      }
}

// ---------------- causal flash attention v2 + SiLU-gate epilogue ----------------
// Block = 128 threads (2 waves), each wave owns 32 Q rows (2 m-tiles) -> 2x
// arithmetic intensity per LDS byte vs v1. Q-tile = 64 rows. K-tile = 64.
// Causal balance: block pairs Q-tiles (i, 31-i) -> every block runs exactly
// 33 k-tiles; grid 16x32 = 512 blocks = 2/CU, all resident.
// K/V staged via gll16 with XOR-swizzled *global* source so the LDS
// fragment reads spread over all 32 banks (LDS dest must stay lane*16).
// Ks logical (row,chunk16B c): phys chunk = row*32 + (c ^ (row&31))
// Vts logical (d-row, chunk c): phys chunk = row*8  + (c ^ (row&7))
// P scratch (aliases Ks region): per wave 2 m-tiles of 16 x 72 (pad) bf16.
__global__ __launch_bounds__(128, 1) void flash(const bf16* __restrict__ Q,
    const bf16* __restrict__ K, const bf16* __restrict__ Vt,
    const bf16* __restrict__ QKV, bf16* __restrict__ Og) {
  __shared__ alignas(16) bf16 smem[32768];
  bf16* Ks = smem;
  bf16* Vts = smem + 16384;

  int pairi = blockIdx.x;  // 0..15
  int bh = blockIdx.y, b = bh >> 4, h = bh & 15, kvh = h >> 2;
  int tid = threadIdx.x, wave = tid >> 6, lane = tid & 63;
  int quad = lane >> 4, l15 = lane & 15;

  const bf16* Qh = Q + ((size_t)(b * 16 + h) * 2048) * 256;
  const bf16* Kb = K + ((size_t)(b * 4 + kvh) * 2048) * 256;
  const bf16* Vb = Vt + ((size_t)(b * 4 + kvh) * 256) * 2048;
  const fvec4 FZ = {0.f, 0.f, 0.f, 0.f};

  for (int half = 0; half < 2; ++half) {
    int qt = half ? (31 - pairi) : pairi;
    int q0 = qt * 64;

    // Q fragments resident, pre-scaled by 1/sqrt(256)=2^-4 (exact in bf16)
    bvec8 qf[2][8];
#pragma unroll
    for (int mt = 0; mt < 2; ++mt) {
      int row = q0 + wave * 32 + mt * 16 + l15;
#pragma unroll
      for (int kk = 0; kk < 8; ++kk) {
        bvec8 v = *(const bvec8*)(Qh + (size_t)row * 256 + kk * 32 + quad * 8);
#pragma unroll
        for (int j = 0; j < 8; ++j) v[j] = (bf16)((float)v[j] * 0.0625f);
        qf[mt][kk] = v;
      }
    }

    fvec4 acc[2][16];
#pragma unroll
    for (int mt = 0; mt < 2; ++mt)
#pragma unroll
      for (int i = 0; i < 16; ++i) acc[mt][i] = FZ;
    float m_run[2][4], l_run[2][4];
#pragma unroll
    for (int mt = 0; mt < 2; ++mt)
#pragma unroll
      for (int r = 0; r < 4; ++r) { m_run[mt][r] = -3.0e38f; l_run[mt][r] = 0.f; }

    for (int kt = 0; kt <= qt; ++kt) {
      int k0 = kt * 64;
      __syncthreads();  // prior iter's LDS readers done before restaging
#pragma unroll
      for (int i = 0; i < 16; ++i) {
        int seg = wave * 16 + i;  // 0..31, 1KB per gll16
        int krow = seg * 2 + (lane >> 5);
        int kc = (lane & 31) ^ (krow & 31);
        gll16(Kb + (size_t)(k0 + krow) * 256 + kc * 8, Ks + seg * 512);
        int vrow = seg * 8 + (lane >> 3);
        int vc = (lane & 7) ^ (vrow & 7);
        gll16(Vb + (size_t)vrow * 2048 + k0 + vc * 8, Vts + seg * 512);
      }
      __syncthreads();  // tiles visible (barrier drains vmcnt)

      // S = Q K^T; kf shared across the 2 m-tiles
      fvec4 s[2][4];
#pragma unroll
      for (int nt = 0; nt < 4; ++nt) {
        s[0][nt] = FZ; s[1][nt] = FZ;
        int row = nt * 16 + l15;
        int rm = row & 31;
#pragma unroll
        for (int ks = 0; ks < 8; ++ks) {
          int c = ks * 4 + quad;
          bvec8 kf = *(const bvec8*)(Ks + (size_t)row * 256 + (size_t)(c ^ rm) * 8);
          s[0][nt] = __builtin_amdgcn_mfma_f32_16x16x32_bf16(qf[0][ks], kf, s[0][nt], 0, 0, 0);
          s[1][nt] = __builtin_amdgcn_mfma_f32_16x16x32_bf16(qf[1][ks], kf, s[1][nt], 0, 0, 0);
        }
      }
      __syncthreads();  // ALL waves' Ks reads done -> P may alias Ks

      if (kt == qt) {  // only the diagonal tile masks
#pragma unroll
        for (int mt = 0; mt < 2; ++mt)
#pragma unroll
          for (int nt = 0; nt < 4; ++nt)
#pragma unroll
            for (int r = 0; r < 4; ++r)
              if (k0 + nt * 16 + l15 > q0 + wave * 32 + mt * 16 + quad * 4 + r)
                s[mt][nt][r] = -3.0e38f;
      }

      bf16* Pw = smem + wave * 2304;  // 2 x 16 x 72 bf16, aliases Ks
      float alpha[2][4];
#pragma unroll
      for (int mt = 0; mt < 2; ++mt) {
        float rs[4];
#pragma unroll
        for (int r = 0; r < 4; ++r) {
          float m = fmaxf(fmaxf(s[mt][0][r], s[mt][1][r]),
                          fmaxf(s[mt][2][r], s[mt][3][r]));
#pragma unroll
          for (int off = 8; off; off >>= 1) m = fmaxf(m, __shfl_xor(m, off));
          float Mn = fmaxf(m_run[mt][r], m);
          alpha[mt][r] = __expf(m_run[mt][r] - Mn);
          m_run[mt][r] = Mn;
          rs[r] = 0.f;
        }
#pragma unroll
        for (int nt = 0; nt < 4; ++nt)
#pragma unroll
          for (int r = 0; r < 4; ++r) {
            float p = __expf(s[mt][nt][r] - m_run[mt][r]);
            rs[r] += p;
            Pw[mt * 1152 + (quad * 4 + r) * 72 + nt * 16 + l15] = (bf16)p;
          }
#pragma unroll
        for (int r = 0; r < 4; ++r) {
#pragma unroll
          for (int off = 8; off; off >>= 1) rs[r] += __shfl_xor(rs[r], off);
          l_run[mt][r] = l_run[mt][r] * alpha[mt][r] + rs[r];
        }
#pragma unroll
        for (int nt = 0; nt < 16; ++nt)
#pragma unroll
          for (int r = 0; r < 4; ++r) acc[mt][nt][r] *= alpha[mt][r];
      }
      __syncthreads();  // P writes visible

      // O += P (2x16x64) * Vtile (64x256); vf shared across the 2 m-tiles
#pragma unroll
      for (int ks = 0; ks < 2; ++ks) {
        bvec8 pf0 = *(const bvec8*)(Pw + l15 * 72 + ks * 32 + quad * 8);
        bvec8 pf1 = *(const bvec8*)(Pw + 1152 + l15 * 72 + ks * 32 + quad * 8);
#pragma unroll
        for (int nt = 0; nt < 16; ++nt) {
          int row = nt * 16 + l15;
          int c = ks * 4 + quad;
          bvec8 vf = *(const bvec8*)(Vts + (size_t)row * 64 + (size_t)(c ^ (row & 7)) * 8);
          acc[0][nt] = __builtin_amdgcn_mfma_f32_16x16x32_bf16(pf0, vf, acc[0][nt], 0, 0, 0);
          acc[1][nt] = __builtin_amdgcn_mfma_f32_16x16x32_bf16(pf1, vf, acc[1][nt], 0, 0, 0);
        }
      }
    }

    // epilogue: O/l * silu(gate), token-major (b*2048+l, h*256+d)
#pragma unroll
    for (int mt = 0; mt < 2; ++mt)
#pragma unroll
      for (int r = 0; r < 4; ++r) {
        int token = b * 2048 + q0 + wave * 32 + mt * 16 + quad * 4 + r;
        float inv = 1.0f / l_run[mt][r];
#pragma unroll
        for (int nt = 0; nt < 16; ++nt) {
          int col = h * 256 + nt * 16 + l15;
          float g = (float)QKV[(size_t)token * NQKV + 4096 + col];
          float silu = g / (1.0f + __expf(-g));
          Og[(size_t)token * 4096 + col] = (bf16)(acc[mt][nt][r] * inv * silu);
        }
      }
  }
}

extern "C" void kernel_launch(void* const* d_in, const int* in_sizes, int n_in,
                              void* d_out, int out_size, void* d_ws, size_t ws_size,
                              hipStream_t stream) {
  const float* hs   = (const float*)d_in[0];
  const float* cosT = (const float*)d_in[1];
  const float* sinT = (const float*)d_in[2];
  const float* Wq   = (const float*)d_in[3];
  const float* Wk   = (const float*)d_in[4];
  const float* Wv   = (const float*)d_in[5];
  const float* Wo   = (const float*)d_in[6];
  const float* qw   = (const float*)d_in[7];
  const float* kw   = (const float*)d_in[8];
  float* out = (float*)d_out;

  char* p = (char*)d_ws;
  auto alloc = [&](size_t bytes) {
    char* r = p;
    p += (bytes + 255) & ~(size_t)255;
    return r;
  };
  bf16* Xb    = (bf16*)alloc((size_t)4096 * 2560 * 2);
  bf16* Wqkvt = (bf16*)alloc((size_t)10240 * 2560 * 2);
  bf16* Wot   = (bf16*)alloc((size_t)2560 * 4096 * 2);
  bf16* QKV   = (bf16*)alloc((size_t)4096 * 10240 * 2);
  bf16* Qn    = (bf16*)alloc((size_t)2 * 16 * 2048 * 256 * 2);
  bf16* Kn    = (bf16*)alloc((size_t)2 * 4 * 2048 * 256 * 2);
  bf16* Vtb   = (bf16*)alloc((size_t)2 * 4 * 256 * 2048 * 2);
  bf16* Og    = (bf16*)alloc((size_t)4096 * 4096 * 2);

  cvt_f32_bf16<<<10240, 256, 0, stream>>>(hs, Xb, 4096 * 2560);
  wtrans<<<dim3(128, 40), 256, 0, stream>>>(Wq, Wqkvt, 2560, 8192);
  wtrans<<<dim3(16, 40), 256, 0, stream>>>(Wk, Wqkvt + (size_t)8192 * 2560, 2560, 1024);
  wtrans<<<dim3(16, 40), 256, 0, stream>>>(Wv, Wqkvt + (size_t)9216 * 2560, 2560, 1024);
  wtrans<<<dim3(40, 64), 256, 0, stream>>>(Wo, Wot, 4096, 2560);

  gemm_bt<bf16><<<dim3(80, 32), 256, 0, stream>>>(Xb, Wqkvt, QKV, 10240, 2560);

  norm_rope<<<20480, 256, 0, stream>>>(QKV, cosT, sinT, qw, kw, Qn, Kn);
  vtrans<<<dim3(32, 4, 8), 256, 0, stream>>>(QKV, Vtb);

  flash<<<dim3(16, 32), 128, 0, stream>>>(Qn, Kn, Vtb, QKV, Og);

  gemm_bt<float><<<dim3(20, 32), 256, 0, stream>>>(Og, Wot, out, 2560, 4096);
}